// Round 2
// baseline (2750.169 us; speedup 1.0000x reference)
//
#include <hip/hip_runtime.h>
#include <hip/hip_bf16.h>

// Problem constants (hardcoded in the reference module)
#define P 4
#define NN 100000
#define MM 50000
#define EE 400000
#define DD 128
#define ROWS 32

#define SCH 4096           // scan chunk
#define NCH 13             // ceil(MM / SCH)

typedef __attribute__((ext_vector_type(8))) short bf16x8;   // 8 bf16 in 4 VGPRs
typedef __attribute__((ext_vector_type(4))) float f32x4;    // MFMA accumulator

__device__ inline unsigned short bf16u(float x) {
    __hip_bfloat16 h = __float2bfloat16(x);                 // RNE
    return __builtin_bit_cast(unsigned short, h);
}
__device__ inline float bf16f(unsigned short u) {
    return __builtin_bit_cast(float, (unsigned)u << 16);
}
__device__ inline uint2 packhl4(float4 v, int lo) {
    unsigned short a0 = bf16u(v.x), a1 = bf16u(v.y), a2 = bf16u(v.z), a3 = bf16u(v.w);
    if (lo) {
        a0 = bf16u(v.x - bf16f(a0)); a1 = bf16u(v.y - bf16f(a1));
        a2 = bf16u(v.z - bf16f(a2)); a3 = bf16u(v.w - bf16f(a3));
    }
    uint2 r; r.x = (unsigned)a0 | ((unsigned)a1 << 16);
    r.y = (unsigned)a2 | ((unsigned)a3 << 16);
    return r;
}
__device__ inline void fma4(float4& a, float w, float4 v) {
    a.x += w * v.x; a.y += w * v.y; a.z += w * v.z; a.w += w * v.w;
}
__device__ inline void xadd32(float4& a) {
    a.x += __shfl_xor(a.x, 32);
    a.y += __shfl_xor(a.y, 32);
    a.z += __shfl_xor(a.z, 32);
    a.w += __shfl_xor(a.w, 32);
}

// ---------------------------------------------------------------------------
// K1: per-(s,d) pair: count original-dst degree (mean weights). One atomic/edge.
__global__ __launch_bounds__(256) void k_count(const int* __restrict__ edge_dst,
                                               int* __restrict__ deg_orig) {
    int i = blockIdx.x * 256 + threadIdx.x;
    if (i >= P * P * EE) return;
    int pair = i / EE;
    atomicAdd(&deg_orig[pair * MM + edge_dst[i]], 1);
}

// K1b: derive merged-row counts from deg_orig and self-term counts.
__global__ __launch_bounds__(256) void k_derive(const int* __restrict__ merge,
                                                const int* __restrict__ deg_orig,
                                                int* __restrict__ cnt_n,
                                                int* __restrict__ cnt_s) {
    int i = blockIdx.x * 256 + threadIdx.x;
    if (i >= P * P * MM) return;
    int pair = i / MM;
    int r = i - pair * MM;
    int s = pair >> 2, d = pair & 3;
    int m = (s == d) ? r : merge[i];
    atomicAdd(&cnt_n[pair * MM + m], deg_orig[i]);
    atomicAdd(&cnt_s[pair * MM + m], 1);
}

// ---------------------------------------------------------------------------
// K2a: per-chunk partial sums (grid = 2*16*NCH = 416 blocks).
__global__ __launch_bounds__(256) void k_scan1(const int* __restrict__ cnt_n,
                                               const int* __restrict__ cnt_s,
                                               int* __restrict__ partial) {
    int blk = blockIdx.x;
    int chunk = blk % NCH, wp = blk / NCH;
    const int* cnt = ((wp >> 4) ? cnt_s : cnt_n) + (wp & 15) * MM;
    int base = chunk * SCH;
    int end = min(base + SCH, MM);
    int sum = 0;
    for (int i = base + (int)threadIdx.x; i < end; i += 256) sum += cnt[i];
    #pragma unroll
    for (int off = 32; off > 0; off >>= 1) sum += __shfl_down(sum, off);
    __shared__ int sh[4];
    if ((threadIdx.x & 63) == 0) sh[threadIdx.x >> 6] = sum;
    __syncthreads();
    if (threadIdx.x == 0) partial[blk] = sh[0] + sh[1] + sh[2] + sh[3];
}

// K2b: per-chunk exclusive scan + chunk offset; write rs; zero cnt (cursor).
__global__ __launch_bounds__(256) void k_scan2(int* __restrict__ cnt_n,
                                               int* __restrict__ rs_n,
                                               int* __restrict__ cnt_s,
                                               int* __restrict__ rs_s,
                                               const int* __restrict__ partial) {
    int blk = blockIdx.x;
    int chunk = blk % NCH, wp = blk / NCH;
    int which = wp >> 4, pair = wp & 15;
    int* cnt = (which ? cnt_s : cnt_n) + pair * MM;
    int* rs  = (which ? rs_s : rs_n) + pair * (MM + 1);
    __shared__ int sh[256];
    __shared__ int soff;
    if (threadIdx.x == 0) {
        int o = 0;
        for (int c = 0; c < chunk; ++c) o += partial[wp * NCH + c];
        soff = o;
        if (chunk == NCH - 1) rs[MM] = o + partial[wp * NCH + chunk];
    }
    int base = chunk * SCH + (int)threadIdx.x * 16;
    int v[16]; int run = 0;
    #pragma unroll
    for (int j = 0; j < 16; ++j) {
        int i = base + j;
        int c = (i < MM) ? cnt[i] : 0;
        v[j] = run;
        run += c;
    }
    sh[threadIdx.x] = run;
    __syncthreads();
    for (int off = 1; off < 256; off <<= 1) {
        int t = (threadIdx.x >= (unsigned)off) ? sh[threadIdx.x - off] : 0;
        __syncthreads();
        sh[threadIdx.x] += t;
        __syncthreads();
    }
    int texc = sh[threadIdx.x] - run;
    int o = soff + texc;
    #pragma unroll
    for (int j = 0; j < 16; ++j) {
        int i = base + j;
        if (i < MM) { rs[i] = o + v[j]; cnt[i] = 0; }
    }
}

// ---------------------------------------------------------------------------
// K3: counting-sort neigh edges into merged-dst CSR; (src, weight) packed int2.
__global__ __launch_bounds__(256) void k_fill(const int* __restrict__ edge_src,
                                              const int* __restrict__ edge_dst,
                                              const int* __restrict__ merge,
                                              const int* __restrict__ deg_orig,
                                              const int* __restrict__ rs_n,
                                              int* __restrict__ cur_n,
                                              int2* __restrict__ csp) {
    int i = blockIdx.x * 256 + threadIdx.x;
    if (i >= P * P * EE) return;
    int pair = i / EE;
    int s = pair >> 2, d = pair & 3;
    int od = edge_dst[i];
    int m = (s == d) ? od : merge[pair * MM + od];
    float w = 1.0f / fmaxf((float)deg_orig[pair * MM + od], 1.0f);
    int pos = rs_n[pair * (MM + 1) + m] + atomicAdd(&cur_n[pair * MM + m], 1);
    int2 e; e.x = edge_src[i]; e.y = __float_as_int(w);
    csp[(size_t)pair * EE + pos] = e;
}

// K3b: self-term CSR (row r of x[s][:M] contributes to merged row m).
__global__ __launch_bounds__(256) void k_fill_self(const int* __restrict__ merge,
                                                   const int* __restrict__ rs_s,
                                                   int* __restrict__ cur_s,
                                                   int* __restrict__ css) {
    int i = blockIdx.x * 256 + threadIdx.x;
    if (i >= P * P * MM) return;
    int pair = i / MM;
    int r = i - pair * MM;
    int s = pair >> 2, d = pair & 3;
    int m = (s == d) ? r : merge[i];
    int pos = rs_s[pair * (MM + 1) + m] + atomicAdd(&cur_s[pair * MM + m], 1);
    css[pair * MM + pos] = r;
}

// ---------------------------------------------------------------------------
// K3c: split weights into hi/lo bf16, packed fragment-ready:
//      Bpk[s][hl(2)][kchunk(32)][col(128)][8k]  (chunks 0-15 = W_self rows,
//      16-31 = W_neigh rows). 512 KB; overlaid on dead deg_orig space.
__global__ __launch_bounds__(256) void k_pack_w(const float* __restrict__ Ws,
                                                const float* __restrict__ Wn,
                                                unsigned short* __restrict__ Bpk) {
    int t = blockIdx.x * 256 + threadIdx.x;     // 4s * 32c * 128col = 16384
    if (t >= 4 * 32 * 128) return;
    int s = t >> 12;
    int rem = t & 4095;                         // c*128 + col
    int c = rem >> 7, col = rem & 127;
    const float* W = (c < 16) ? (Ws + (size_t)s * DD * DD + (c * 8) * DD + col)
                              : (Wn + (size_t)s * DD * DD + ((c - 16) * 8) * DD + col);
    size_t ohi = ((size_t)(s * 2 + 0) * 4096 + rem) * 8;
    size_t olo = ((size_t)(s * 2 + 1) * 4096 + rem) * 8;
    #pragma unroll
    for (int j = 0; j < 8; ++j) {
        float v = W[(size_t)j * DD];
        unsigned short h = bf16u(v);
        unsigned short l = bf16u(v - bf16f(h));
        Bpk[ohi + j] = h;
        Bpk[olo + j] = l;
    }
}

// ---------------------------------------------------------------------------
// K4: fused per-d kernel. MLP-deep gather (2 edges/load via half-wave float4,
//     row-pair interleave, hoisted range loads) -> hi/lo bf16 swizzled LDS
//     -> 16x16x32 bf16 MFMA GEMM (hi*hi + lo*hi + hi*lo, fp32 accum).
__global__ __launch_bounds__(256, 4) void k_fused(const float* __restrict__ x_all,
                                                  const float* __restrict__ b_all,
                                                  const int* __restrict__ rs_n_all,
                                                  const int2* __restrict__ csp_all,
                                                  const int* __restrict__ rs_s_all,
                                                  const int* __restrict__ css_all,
                                                  const unsigned short* __restrict__ Bpk,
                                                  float* __restrict__ out) {
    int d = blockIdx.y;
    int m0 = blockIdx.x * ROWS;
    int tid = threadIdx.x;
    int lane = tid & 63, wv = tid >> 6;
    int l15 = lane & 15, kg = lane >> 4;
    int half = lane >> 5, l31 = lane & 31;
    int col = l31 << 2;                     // this lane's 4-col group

    // A_hi [32 rows][256 k] bf16 @0, A_lo @16384. Row stride 512 B.
    // XOR-swizzle byte ^= ((row&7)<<4) to break the 512B-stride bank conflict.
    __shared__ char lds[32768];

    f32x4 acc[2][2];
    f32x4 zero = {0.f, 0.f, 0.f, 0.f};
    acc[0][0] = zero; acc[0][1] = zero; acc[1][0] = zero; acc[1][1] = zero;

    for (int s = 0; s < P; ++s) {
        int pair = s * P + d;
        const float* x   = x_all + (size_t)s * NN * DD;
        const int* rsn   = rs_n_all + (size_t)pair * (MM + 1);
        const int2* csp  = csp_all + (size_t)pair * EE;
        const int* rss   = rs_s_all + (size_t)pair * (MM + 1);
        const int* css   = css_all + (size_t)pair * MM;

        // ---- hoist all CSR range loads for this wave's 8 rows (1 round)
        int sa0g[4], sa1g[4], na0g[4], na1g[4];
        int sb0g[4], sb1g[4], nb0g[4], nb1g[4];
        #pragma unroll
        for (int g = 0; g < 4; ++g) {
            int mA = m0 + wv + 4 * g, mB = mA + 16;
            bool vA = mA < MM, vB = mB < MM;
            sa0g[g] = vA ? rss[mA] : 0;     sa1g[g] = vA ? rss[mA + 1] : 0;
            na0g[g] = vA ? rsn[mA] : 0;     na1g[g] = vA ? rsn[mA + 1] : 0;
            sb0g[g] = vB ? rss[mB] : 0;     sb1g[g] = vB ? rss[mB + 1] : 0;
            nb0g[g] = vB ? rsn[mB] : 0;     nb1g[g] = vB ? rsn[mB + 1] : 0;
        }

        // ---- gather: row pairs (rA, rA+16); half-wave = one edge's full row
        for (int g = 0; g < 4; ++g) {
            int rA = wv + 4 * g, rB = rA + 16;
            int sa0 = sa0g[g], sa1 = sa1g[g], na0 = na0g[g], na1 = na1g[g];
            int sb0 = sb0g[g], sb1 = sb1g[g], nb0 = nb0g[g], nb1 = nb1g[g];
            float4 aSA = {0,0,0,0}, aNA = {0,0,0,0};
            float4 aSB = {0,0,0,0}, aNB = {0,0,0,0};

            // self (w = 1): 2 edges/row/iter
            int lsA = max(sa1 - 1, 0), lsB = max(sb1 - 1, 0);
            while (sa0 < sa1 || sb0 < sb1) {
                int eA = sa0 + half, eB = sb0 + half;
                int iA = css[min(eA, lsA)];
                int iB = css[min(eB, lsB)];
                float4 fA = *(const float4*)(x + (size_t)iA * DD + col);
                float4 fB = *(const float4*)(x + (size_t)iB * DD + col);
                fma4(aSA, (eA < sa1) ? 1.f : 0.f, fA);
                fma4(aSB, (eB < sb1) ? 1.f : 0.f, fB);
                sa0 += 2; sb0 += 2;
            }

            // neigh: 8 edges/row/iter (4 half-wave loads each)
            int lnA = max(na1 - 1, 0), lnB = max(nb1 - 1, 0);
            while (na0 < na1 || nb0 < nb1) {
                int2 ea[4], eb[4];
                #pragma unroll
                for (int q = 0; q < 4; ++q) ea[q] = csp[min(na0 + 2 * q + half, lnA)];
                #pragma unroll
                for (int q = 0; q < 4; ++q) eb[q] = csp[min(nb0 + 2 * q + half, lnB)];
                float4 va[4], vb[4];
                #pragma unroll
                for (int q = 0; q < 4; ++q)
                    va[q] = *(const float4*)(x + (size_t)ea[q].x * DD + col);
                #pragma unroll
                for (int q = 0; q < 4; ++q)
                    vb[q] = *(const float4*)(x + (size_t)eb[q].x * DD + col);
                #pragma unroll
                for (int q = 0; q < 4; ++q) {
                    fma4(aNA, (na0 + 2 * q + half < na1) ? __int_as_float(ea[q].y) : 0.f, va[q]);
                    fma4(aNB, (nb0 + 2 * q + half < nb1) ? __int_as_float(eb[q].y) : 0.f, vb[q]);
                }
                na0 += 8; nb0 += 8;
            }

            // combine even/odd-edge halves (lane l <-> l+32)
            xadd32(aSA); xadd32(aNA); xadd32(aSB); xadd32(aNB);

            // hi (half 0) / lo (half 1) bf16 -> swizzled LDS
            char* dst = (char*)lds + (half ? 16384 : 0);
            int xrA = (rA & 7) << 4, xrB = (rB & 7) << 4;
            *(uint2*)(dst + rA * 512 + ((col * 2) ^ xrA))       = packhl4(aSA, half);
            *(uint2*)(dst + rA * 512 + ((256 + col * 2) ^ xrA)) = packhl4(aNA, half);
            *(uint2*)(dst + rB * 512 + ((col * 2) ^ xrB))       = packhl4(aSB, half);
            *(uint2*)(dst + rB * 512 + ((256 + col * 2) ^ xrB)) = packhl4(aNB, half);
        }
        __syncthreads();

        // ---- MFMA GEMM: acc[32][128] += A[32][256] @ [Ws[s]; Wn[s]]
        {
            int row0 = l15, row1 = 16 + l15;
            int xr = (l15 & 7) << 4;
            const bf16x8* Bh = (const bf16x8*)(Bpk + (size_t)(s * 2 + 0) * 4096 * 8);
            const bf16x8* Bl = (const bf16x8*)(Bpk + (size_t)(s * 2 + 1) * 4096 * 8);
            int colbase = wv * 32 + l15;
            #pragma unroll
            for (int kk = 0; kk < 8; ++kk) {
                int c = kk * 4 + kg;
                int co = (c * 16) ^ xr;
                bf16x8 ah0 = *(const bf16x8*)(lds + row0 * 512 + co);
                bf16x8 ah1 = *(const bf16x8*)(lds + row1 * 512 + co);
                bf16x8 al0 = *(const bf16x8*)(lds + 16384 + row0 * 512 + co);
                bf16x8 al1 = *(const bf16x8*)(lds + 16384 + row1 * 512 + co);
                size_t bo = (size_t)c * 128 + colbase;
                bf16x8 bh0 = Bh[bo];
                bf16x8 bh1 = Bh[bo + 16];
                bf16x8 bl0 = Bl[bo];
                bf16x8 bl1 = Bl[bo + 16];
                acc[0][0] = __builtin_amdgcn_mfma_f32_16x16x32_bf16(ah0, bh0, acc[0][0], 0, 0, 0);
                acc[0][1] = __builtin_amdgcn_mfma_f32_16x16x32_bf16(ah0, bh1, acc[0][1], 0, 0, 0);
                acc[1][0] = __builtin_amdgcn_mfma_f32_16x16x32_bf16(ah1, bh0, acc[1][0], 0, 0, 0);
                acc[1][1] = __builtin_amdgcn_mfma_f32_16x16x32_bf16(ah1, bh1, acc[1][1], 0, 0, 0);
                acc[0][0] = __builtin_amdgcn_mfma_f32_16x16x32_bf16(al0, bh0, acc[0][0], 0, 0, 0);
                acc[0][1] = __builtin_amdgcn_mfma_f32_16x16x32_bf16(al0, bh1, acc[0][1], 0, 0, 0);
                acc[1][0] = __builtin_amdgcn_mfma_f32_16x16x32_bf16(al1, bh0, acc[1][0], 0, 0, 0);
                acc[1][1] = __builtin_amdgcn_mfma_f32_16x16x32_bf16(al1, bh1, acc[1][1], 0, 0, 0);
                acc[0][0] = __builtin_amdgcn_mfma_f32_16x16x32_bf16(ah0, bl0, acc[0][0], 0, 0, 0);
                acc[0][1] = __builtin_amdgcn_mfma_f32_16x16x32_bf16(ah0, bl1, acc[0][1], 0, 0, 0);
                acc[1][0] = __builtin_amdgcn_mfma_f32_16x16x32_bf16(ah1, bl0, acc[1][0], 0, 0, 0);
                acc[1][1] = __builtin_amdgcn_mfma_f32_16x16x32_bf16(ah1, bl1, acc[1][1], 0, 0, 0);
            }
        }

        // ---- bias: each contributing source row brings one b[s]
        {
            float bv0 = b_all[(size_t)s * DD + wv * 32 + l15];
            float bv1 = b_all[(size_t)s * DD + wv * 32 + 16 + l15];
            #pragma unroll
            for (int rt = 0; rt < 2; ++rt) {
                int mb = m0 + rt * 16 + kg * 4;
                #pragma unroll
                for (int r = 0; r < 4; ++r) {
                    int m = mb + r;
                    if (m < MM) {
                        float cf = (float)(rss[m + 1] - rss[m]);
                        acc[rt][0][r] += cf * bv0;
                        acc[rt][1][r] += cf * bv1;
                    }
                }
            }
        }
        __syncthreads();   // before next s overwrites LDS
    }

    // ---- store. D layout: col = lane&15 (+tile), row = (lane>>4)*4 + reg (+tile)
    float* outd = out + (size_t)d * MM * DD;
    #pragma unroll
    for (int rt = 0; rt < 2; ++rt) {
        #pragma unroll
        for (int r = 0; r < 4; ++r) {
            int m = m0 + rt * 16 + kg * 4 + r;
            if (m >= MM) continue;
            float* o = outd + (size_t)m * DD + wv * 32 + l15;
            o[0]  = acc[rt][0][r];
            o[16] = acc[rt][1][r];
        }
    }
}

// ---------------------------------------------------------------------------
extern "C" void kernel_launch(void* const* d_in, const int* in_sizes, int n_in,
                              void* d_out, int out_size, void* d_ws, size_t ws_size,
                              hipStream_t stream) {
    const float* x     = (const float*)d_in[0];   // [P][N][D]
    const float* Ws    = (const float*)d_in[1];   // [P][D][D]
    const float* Wn    = (const float*)d_in[2];   // [P][D][D]
    const float* b     = (const float*)d_in[3];   // [P][D]
    const int*   esrc  = (const int*)d_in[4];     // [P][P][E]
    const int*   edst  = (const int*)d_in[5];     // [P][P][E]
    const int*   merge = (const int*)d_in[6];     // [P][P][M]
    float* out = (float*)d_out;                   // [P][M][D]

    // workspace layout (~70.4 MB total, unchanged footprint):
    int* deg_orig = (int*)d_ws;                   // [16*M]; dead after k_fill -> Bpk
    int* cnt_n    = deg_orig + 16 * MM;           // [16*M] counts -> cursor
    int* cnt_s    = cnt_n + 16 * MM;              // [16*M] counts -> cursor
    int* rs_n     = cnt_s + 16 * MM;              // [16*(M+1)]
    int* rs_s     = rs_n + 16 * (MM + 1);         // [16*(M+1)]
    int2* csp     = (int2*)(rs_s + 16 * (MM + 1));// [16*E] packed (src, w)
    int* css      = (int*)(csp + (size_t)16 * EE);// [16*M]
    int* partial  = (int*)csp;                    // scan partials overlay (pre-fill)
    unsigned short* Bpk = (unsigned short*)d_ws;  // overlay on deg_orig

    hipMemsetAsync(d_ws, 0, sizeof(int) * (size_t)16 * MM * 3, stream);  // deg+cnt_n+cnt_s

    int eblocks = (P * P * EE + 255) / 256;       // 25000
    int mblocks16 = (P * P * MM + 255) / 256;     // 3125
    k_count<<<eblocks, 256, 0, stream>>>(edst, deg_orig);
    k_derive<<<mblocks16, 256, 0, stream>>>(merge, deg_orig, cnt_n, cnt_s);
    k_scan1<<<2 * 16 * NCH, 256, 0, stream>>>(cnt_n, cnt_s, partial);
    k_scan2<<<2 * 16 * NCH, 256, 0, stream>>>(cnt_n, rs_n, cnt_s, rs_s, partial);
    k_fill<<<eblocks, 256, 0, stream>>>(esrc, edst, merge, deg_orig, rs_n, cnt_n, csp);
    k_fill_self<<<mblocks16, 256, 0, stream>>>(merge, rs_s, cnt_s, css);
    k_pack_w<<<64, 256, 0, stream>>>(Ws, Wn, Bpk);  // overwrites deg_orig (dead)

    dim3 gfused((MM + ROWS - 1) / ROWS, P);       // (1563, 4)
    k_fused<<<gfused, 256, 0, stream>>>(x, b, rs_n, csp, rs_s, css, Bpk, out);
}